// Round 8
// baseline (492.697 us; speedup 1.0000x reference)
//
#include <hip/hip_runtime.h>
#include <hip/hip_cooperative_groups.h>
#include <cstdint>
#include <cstddef>

namespace cg = cooperative_groups;

#define B_DIM 8
#define L_DIM 33600
#define N_DIM 128
#define C_DIM 80
#define K_TOP 13
#define EPS_F 1e-9f
#define CAP 4096      // per-(b,n) bucket; max plausible inside ~2600 (mean+30sigma)
#define GRID_X 1024   // 4 blocks/CU on 256 CUs -> cooperative co-residency guaranteed
#define NCHUNK 132    // ceil(L_DIM / 256)

// Bit-exact replica of the reference IoU (f32, no FMA contraction, same op order).
__device__ __forceinline__ float iou_pair(float g0, float g1, float g2, float g3,
                                          float p0, float p1, float p2, float p3) {
    float ltx = fmaxf(g0, p0), lty = fmaxf(g1, p1);
    float rbx = fminf(g2, p2), rby = fminf(g3, p3);
    float wx = fmaxf(__fsub_rn(rbx, ltx), 0.0f);
    float wy = fmaxf(__fsub_rn(rby, lty), 0.0f);
    float inter = __fmul_rn(wx, wy);
    float ag = __fmul_rn(__fsub_rn(g2, g0), __fsub_rn(g3, g1));
    float ap = __fmul_rn(__fsub_rn(p2, p0), __fsub_rn(p3, p1));
    float den = __fadd_rn(__fsub_rn(__fadd_rn(ag, ap), inter), EPS_F);
    float iou = __fdiv_rn(inter, den);
    if (iou > 1.0f) iou = 0.0f;            // (1.0 + 1e-9) rounds to 1.0f in f32
    iou = fminf(fmaxf(iou, 0.0f), 1.0f);
    return iou;
}

// Sortable key: (truncated double bits of s>=0) | (0xFFFF - l) in low 16.
// Larger key == (higher value, then lower anchor index). Keys are unique.
__device__ __forceinline__ unsigned long long make_key(double s, int l) {
    unsigned long long sb = (unsigned long long)__double_as_longlong(s);
    return (sb & 0xFFFFFFFFFFFF0000ull) | (unsigned long long)(0xFFFF - l);
}

// Single cooperative kernel: zero -> push -> top13 -> assign -> out,
// separated by grid.sync(). Phase bodies identical to the verified R7
// kernels (returns converted to guards so every thread reaches each sync).
__global__ __launch_bounds__(256, 4) void k_fused(
    const float* __restrict__ psc, const float* __restrict__ pbox,
    const float* __restrict__ pts, const int* __restrict__ glbl,
    const float* __restrict__ gbox, const float* __restrict__ gpad,
    const int* __restrict__ bgp,
    unsigned long long* __restrict__ posbits, ulonglong2* __restrict__ spat,
    int* __restrict__ cnt, unsigned short* __restrict__ bucket,
    int* __restrict__ fin_out, float* __restrict__ alat,
    float* __restrict__ maxal, float* __restrict__ maxio,
    float* __restrict__ out_lab, float* __restrict__ out_box,
    float* __restrict__ out_sc)
{
    cg::grid_group grid = cg::this_grid();
    const int blk = blockIdx.x, t = threadIdx.x;
    const int lane = t & 63, wid = t >> 6;

    __shared__ float4 gb[N_DIM];
    __shared__ float  gp[N_DIM];
    __shared__ int    lcnt[N_DIM];
    __shared__ int    gbase[N_DIM];
    __shared__ int    gli[N_DIM];
    __shared__ unsigned long long wl[4 * K_TOP];
    __shared__ float  snf[16];
    __shared__ int    scl[16];

    // ---------------- Phase 0: zero accumulated buffers ----------------
    {
        ulonglong2* posb2 = (ulonglong2*)posbits;
        const int gid = blk * 256 + t;                       // 262144 threads
        for (int i = gid; i < B_DIM * L_DIM; i += GRID_X * 256)
            posb2[i] = make_ulonglong2(0ull, 0ull);
        if (gid < B_DIM * N_DIM) { cnt[gid] = 0; maxal[gid] = 0.0f; maxio[gid] = 0.0f; }
    }
    grid.sync();

    // ---------------- Phase 1: containment mask + bucket scatter ----------------
    for (int ch = blk; ch < B_DIM * NCHUNK; ch += GRID_X) {
        const int b = ch / NCHUNK;
        const int l = (ch % NCHUNK) * 256 + t;
        __syncthreads();                                   // protect LDS reuse
        if (t < N_DIM) {
            gb[t] = reinterpret_cast<const float4*>(gbox)[(size_t)b * N_DIM + t];
            gp[t] = gpad[b * N_DIM + t];
            lcnt[t] = 0;
        }
        __syncthreads();

        const bool inrange = (l < L_DIM);
        unsigned long long m0 = 0ull, m1 = 0ull;
        if (inrange) {
            const float2 ap = reinterpret_cast<const float2*>(pts)[l];
            for (int n = 0; n < N_DIM; ++n) {
                if (gp[n] <= 0.0f) continue;               // block-uniform skip
                const float4 g = gb[n];
                bool in = (ap.x >= g.x && ap.x <= g.z && ap.y >= g.y && ap.y <= g.w);
                if (n < 64) m0 |= in ? (1ull << n) : 0ull;
                else        m1 |= in ? (1ull << (n - 64)) : 0ull;
            }
            spat[(size_t)b * L_DIM + l] = make_ulonglong2(m0, m1);
            if (l >= 32) {                                  // l<32 are unconditional seeds
                unsigned long long m = m0;
                while (m) { int n = __ffsll((long long)m) - 1; m &= m - 1; atomicAdd(&lcnt[n], 1); }
                m = m1;
                while (m) { int n = __ffsll((long long)m) - 1; m &= m - 1; atomicAdd(&lcnt[n + 64], 1); }
            }
        }
        __syncthreads();

        if (t < N_DIM) {                                    // one global reservation per (chunk, n)
            int c = lcnt[t];
            gbase[t] = (c > 0) ? atomicAdd(&cnt[b * N_DIM + t], c) : 0;
            lcnt[t] = 0;
        }
        __syncthreads();

        if (inrange && l >= 32) {
            unsigned long long m = m0;
            while (m) {
                int n = __ffsll((long long)m) - 1; m &= m - 1;
                int pos = gbase[n] + atomicAdd(&lcnt[n], 1);
                if (pos < CAP) bucket[(size_t)(b * N_DIM + n) * CAP + pos] = (unsigned short)l;
            }
            m = m1;
            while (m) {
                int n = __ffsll((long long)m) - 1; m &= m - 1;
                int pos = gbase[n + 64] + atomicAdd(&lcnt[n + 64], 1);
                if (pos < CAP) bucket[(size_t)(b * N_DIM + n + 64) * CAP + pos] = (unsigned short)l;
            }
        }
    }
    grid.sync();

    // ---------------- Phase 2: top-13 per (b,n), block == pair ----------------
    {
        const int b = blk >> 7, n = blk & 127;              // 1024 blocks == 1024 pairs
        if (gpad[b * N_DIM + n] > 0.0f) {                   // block-uniform guard
            const float g0 = gbox[(b * N_DIM + n) * 4 + 0];
            const float g1 = gbox[(b * N_DIM + n) * 4 + 1];
            const float g2 = gbox[(b * N_DIM + n) * 4 + 2];
            const float g3 = gbox[(b * N_DIM + n) * 4 + 3];
            int lbl = glbl[b * N_DIM + n];
            lbl = min(max(lbl, 0), C_DIM - 1);
            const float* psb = psc + (size_t)b * L_DIM * C_DIM;
            const float* pbb = pbox + (size_t)b * L_DIM * 4;
            const int bn = b * N_DIM + n;
            const int nc = min(cnt[bn], CAP);

            unsigned long long key[K_TOP];
            #pragma unroll
            for (int k = 0; k < K_TOP; ++k) key[k] = 0ull;

            for (int i = t; i < nc + 32; i += 256) {
                const int l = (i < 32) ? i : (int)bucket[(size_t)bn * CAP + (i - 32)];
                const float2 ap = reinterpret_cast<const float2*>(pts)[l];
                unsigned long long ck = (unsigned long long)(0xFFFF - l);  // s == 0
                if (ap.x >= g0 && ap.x <= g2 && ap.y >= g1 && ap.y <= g3) {
                    const float4 pbv = reinterpret_cast<const float4*>(pbb)[l];
                    float iou = iou_pair(g0, g1, g2, g3, pbv.x, pbv.y, pbv.z, pbv.w);
                    if (iou > 0.0f) {
                        float cs = psb[(size_t)l * C_DIM + lbl];
                        double d = (double)iou, d2 = d * d;
                        ck = make_key((double)cs * (d2 * d2 * d2), l);
                    }
                }
                if (ck > key[K_TOP - 1]) {
                    #pragma unroll
                    for (int k = 0; k < K_TOP; ++k) {
                        unsigned long long hi = key[k] > ck ? key[k] : ck;
                        unsigned long long lo = key[k] > ck ? ck : key[k];
                        key[k] = hi; ck = lo;
                    }
                }
            }

            // per-wave head-merge (4 waves), no barriers
            #pragma unroll 1
            for (int r = 0; r < K_TOP; ++r) {
                unsigned long long best = key[0];
                #pragma unroll
                for (int d = 1; d < 64; d <<= 1) {
                    unsigned long long o = __shfl_xor(best, d, 64);
                    best = o > best ? o : best;
                }
                if (key[0] == best && best != 0ull) {
                    #pragma unroll
                    for (int k = 0; k < K_TOP - 1; ++k) key[k] = key[k + 1];
                    key[K_TOP - 1] = 0ull;
                }
                if (lane == 0) wl[wid * K_TOP + r] = best;
            }
            __syncthreads();

            if (wid == 0) {
                unsigned long long v = (lane < 4 * K_TOP) ? wl[lane] : 0ull;
                #pragma unroll 1
                for (int r = 0; r < K_TOP; ++r) {
                    unsigned long long best = v;
                    #pragma unroll
                    for (int d = 1; d < 64; d <<= 1) {
                        unsigned long long o = __shfl_xor(best, d, 64);
                        best = o > best ? o : best;
                    }
                    if (v == best) v = 0ull;
                    if (lane == 0) {
                        int win = 0xFFFF - (int)(best & 0xFFFFull);
                        atomicOr(&posbits[((size_t)b * L_DIM + win) * 2 + (n >> 6)],
                                 1ULL << (n & 63));
                    }
                }
            }
        }
    }
    grid.sync();

    // ---------------- Phase 3: per-anchor assignment ----------------
    for (int ch = blk; ch < B_DIM * NCHUNK; ch += GRID_X) {
        const int b = ch / NCHUNK;
        const int l = (ch % NCHUNK) * 256 + t;
        __syncthreads();
        if (t < N_DIM) {
            gb[t] = reinterpret_cast<const float4*>(gbox)[(size_t)b * N_DIM + t];
            gli[t] = glbl[b * N_DIM + t];
        }
        __syncthreads();
        if (l >= L_DIM) continue;

        const size_t bl = (size_t)b * L_DIM + l;
        const unsigned long long w0 = posbits[bl * 2 + 0];
        const unsigned long long w1 = posbits[bl * 2 + 1];
        const ulonglong2 sm = spat[bl];
        const unsigned long long p0 = w0 & sm.x, p1 = w1 & sm.y;
        const int pcnt = __popcll(p0) + __popcll(p1);

        int fin = -1;
        if (pcnt == 1) {
            fin = p0 ? (__ffsll(p0) - 1) : (64 + __ffsll(p1) - 1);
        } else if (pcnt > 1) {
            // rare path: best-iou argmax over all 128 GTs (first-max semantics)
            const float4 pb = reinterpret_cast<const float4*>(pbox)[bl];
            float best = -1.0f; int bestn = 0;
            for (int n = 0; n < N_DIM; ++n) {
                float4 g = gb[n];
                float iou = iou_pair(g.x, g.y, g.z, g.w, pb.x, pb.y, pb.z, pb.w);
                if (iou > best) { best = iou; bestn = n; }  // strict > = first-max
            }
            bool posbest = (bestn < 64) ? ((p0 >> bestn) & 1ull) : ((p1 >> (bestn - 64)) & 1ull);
            fin = posbest ? bestn : -1;
        }

        out_lab[bl] = (fin >= 0) ? (float)gli[fin] : (float)bgp[0];
        int gidx = (fin >= 0) ? fin : 0;        // ref gathers boxes with argmax=0 for bg
        reinterpret_cast<float4*>(out_box)[bl] = gb[gidx];
        fin_out[bl] = fin;

        if (fin >= 0) {
            const float4 pb = reinterpret_cast<const float4*>(pbox)[bl];
            float4 g = gb[fin];
            float iou = iou_pair(g.x, g.y, g.z, g.w, pb.x, pb.y, pb.z, pb.w);
            int lb = min(max(gli[fin], 0), C_DIM - 1);
            float cs = psc[bl * C_DIM + lb];
            float al = cs * powf(iou, 6.0f);
            alat[bl] = al;
            // all values >= 0, init 0 -> int-compare == float-compare
            atomicMax((int*)&maxal[b * N_DIM + fin], __float_as_int(al));
            atomicMax((int*)&maxio[b * N_DIM + fin], __float_as_int(iou));
        }
    }
    grid.sync();

    // ---------------- Phase 4: fused norm + one-hot score fill ----------------
    {
        const int NTILES = (B_DIM * L_DIM + 15) / 16;       // 16800 tiles of 16 anchors
        float4* out4 = reinterpret_cast<float4*>(out_sc);
        for (int tile = blk; tile < NTILES; tile += GRID_X) {
            const int a0 = tile * 16;
            __syncthreads();
            if (t < 16) {
                int a = a0 + t;
                float v = 0.0f; int c = -1;
                if (a < B_DIM * L_DIM) {
                    int b = a / L_DIM;
                    int fin = fin_out[a];
                    if (fin >= 0) {
                        v = alat[a] / (maxal[b * N_DIM + fin] + EPS_F) * maxio[b * N_DIM + fin];
                        c = glbl[b * N_DIM + fin];
                    }
                }
                snf[t] = v; scl[t] = c;
            }
            __syncthreads();
            for (int j = t; j < 16 * 20; j += 256) {
                int ai = j / 20;
                int a = a0 + ai;
                if (a >= B_DIM * L_DIM) continue;
                int c0 = (j - ai * 20) * 4;
                float v = snf[ai]; int cl = scl[ai];
                float4 o;
                o.x = (c0 + 0 == cl) ? v : 0.0f;
                o.y = (c0 + 1 == cl) ? v : 0.0f;
                o.z = (c0 + 2 == cl) ? v : 0.0f;
                o.w = (c0 + 3 == cl) ? v : 0.0f;
                out4[(size_t)a * 20 + (j - ai * 20)] = o;
            }
        }
    }
}

extern "C" void kernel_launch(void* const* d_in, const int* in_sizes, int n_in,
                              void* d_out, int out_size, void* d_ws, size_t ws_size,
                              hipStream_t stream)
{
    const float* psc  = (const float*)d_in[0];   // [B,L,C]
    const float* pbox = (const float*)d_in[1];   // [B,L,4]
    const float* pts  = (const float*)d_in[2];   // [1,L,2]
    const int*   glbl = (const int*)d_in[3];     // [B,N,1]
    const float* gbox = (const float*)d_in[4];   // [B,N,4]
    const float* gpad = (const float*)d_in[5];   // [B,N,1]
    const int*   bgp  = (const int*)d_in[6];     // scalar (=C)

    // workspace layout (16-byte aligned blocks)
    const size_t P = (size_t)B_DIM * L_DIM * 2 * sizeof(unsigned long long); // 4,300,800
    char* w = (char*)d_ws;
    unsigned long long* posbits = (unsigned long long*)w;                    // P bytes
    float* maxal = (float*)(w + P);                                          // 4096 B
    float* maxio = (float*)(w + P + 4096);                                   // 4096 B
    int*   cnt   = (int*)  (w + P + 8192);                                   // 4096 B
    ulonglong2* spat = (ulonglong2*)(w + P + 12288);                         // P bytes
    int*   fin   = (int*)  (w + 2 * P + 12288);                              // 1,075,200 B
    float* alat  = (float*)(w + 2 * P + 12288 + 1075200);                    // 1,075,200 B
    unsigned short* bucket = (unsigned short*)(w + 2 * P + 12288 + 2 * 1075200); // 8 MB

    float* out_lab = (float*)d_out;                              // [B,L]
    float* out_box = out_lab + (size_t)B_DIM * L_DIM;            // [B,L,4]
    float* out_sc  = out_box + (size_t)B_DIM * L_DIM * 4;        // [B,L,C]

    void* args[] = {
        (void*)&psc, (void*)&pbox, (void*)&pts, (void*)&glbl, (void*)&gbox,
        (void*)&gpad, (void*)&bgp,
        (void*)&posbits, (void*)&spat, (void*)&cnt, (void*)&bucket,
        (void*)&fin, (void*)&alat, (void*)&maxal, (void*)&maxio,
        (void*)&out_lab, (void*)&out_box, (void*)&out_sc
    };
    hipLaunchCooperativeKernel((const void*)k_fused, dim3(GRID_X), dim3(256),
                               args, 0, stream);
}

// Round 9
// 90.439 us; speedup vs baseline: 5.4478x; 5.4478x over previous
//
#include <hip/hip_runtime.h>
#include <cstdint>
#include <cstddef>

#define B_DIM 8
#define L_DIM 33600
#define N_DIM 128
#define C_DIM 80
#define K_TOP 13
#define EPS_F 1e-9f
#define CAP 4096      // per-(b,n) bucket; max plausible inside ~2600 (mean+30sigma)

// Bit-exact replica of the reference IoU (f32, no FMA contraction, same op order).
__device__ __forceinline__ float iou_pair(float g0, float g1, float g2, float g3,
                                          float p0, float p1, float p2, float p3) {
    float ltx = fmaxf(g0, p0), lty = fmaxf(g1, p1);
    float rbx = fminf(g2, p2), rby = fminf(g3, p3);
    float wx = fmaxf(__fsub_rn(rbx, ltx), 0.0f);
    float wy = fmaxf(__fsub_rn(rby, lty), 0.0f);
    float inter = __fmul_rn(wx, wy);
    float ag = __fmul_rn(__fsub_rn(g2, g0), __fsub_rn(g3, g1));
    float ap = __fmul_rn(__fsub_rn(p2, p0), __fsub_rn(p3, p1));
    float den = __fadd_rn(__fsub_rn(__fadd_rn(ag, ap), inter), EPS_F);
    float iou = __fdiv_rn(inter, den);
    if (iou > 1.0f) iou = 0.0f;            // (1.0 + 1e-9) rounds to 1.0f in f32
    iou = fminf(fmaxf(iou, 0.0f), 1.0f);
    return iou;
}

// Sortable key: (truncated double bits of s>=0) | (0xFFFF - l) in low 16.
// Larger key == (higher value, then lower anchor index). Keys are unique.
__device__ __forceinline__ unsigned long long make_key(double s, int l) {
    unsigned long long sb = (unsigned long long)__double_as_longlong(s);
    return (sb & 0xFFFFFFFFFFFF0000ull) | (unsigned long long)(0xFFFF - l);
}

// K_zero: zero the small accumulated regions (cnt + maxal + maxio).
__global__ __launch_bounds__(1024) void k_zero(
    int* __restrict__ cnt, float* __restrict__ maxal, float* __restrict__ maxio)
{
    const int t = threadIdx.x;            // one block, 1024 threads
    cnt[t] = 0;
    maxal[t] = 0.0f;
    maxio[t] = 0.0f;
}

// K_push: one thread per anchor. Zeroes its anchor's posbits slot (coalesced),
// computes containment mask vs 128 GTs (LDS broadcast), stores the mask
// (consumed by k_assign), then LDS-aggregated two-phase bucket scatter
// (l>=32 only; l<32 are unconditional seeds downstream).
__global__ __launch_bounds__(256) void k_push(
    const float* __restrict__ pts, const float* __restrict__ gbox,
    const float* __restrict__ gpad,
    int* __restrict__ cnt, unsigned short* __restrict__ bucket,
    ulonglong2* __restrict__ spat, ulonglong2* __restrict__ posb2)
{
    const int b = blockIdx.y, t = threadIdx.x;
    __shared__ float4 gb[N_DIM];
    __shared__ float  gp[N_DIM];
    __shared__ int    lcnt[N_DIM];
    __shared__ int    gbase[N_DIM];
    if (t < N_DIM) {
        gb[t] = reinterpret_cast<const float4*>(gbox)[(size_t)b * N_DIM + t];
        gp[t] = gpad[b * N_DIM + t];
        lcnt[t] = 0;
    }
    __syncthreads();

    const int l = blockIdx.x * 256 + t;
    const bool inrange = (l < L_DIM);

    unsigned long long m0 = 0ull, m1 = 0ull;
    if (inrange) {
        posb2[(size_t)b * L_DIM + l] = make_ulonglong2(0ull, 0ull);  // memset replacement
        const float2 ap = reinterpret_cast<const float2*>(pts)[l];
        for (int n = 0; n < N_DIM; ++n) {
            if (gp[n] <= 0.0f) continue;          // block-uniform skip of padded GTs
            const float4 g = gb[n];
            bool in = (ap.x >= g.x && ap.x <= g.z && ap.y >= g.y && ap.y <= g.w);
            if (n < 64) m0 |= in ? (1ull << n) : 0ull;
            else        m1 |= in ? (1ull << (n - 64)) : 0ull;
        }
        spat[(size_t)b * L_DIM + l] = make_ulonglong2(m0, m1);
        if (l >= 32) {
            // Phase A: local counts (no return-value dependence)
            unsigned long long m = m0;
            while (m) { int n = __ffsll((long long)m) - 1; m &= m - 1; atomicAdd(&lcnt[n], 1); }
            m = m1;
            while (m) { int n = __ffsll((long long)m) - 1; m &= m - 1; atomicAdd(&lcnt[n + 64], 1); }
        }
    }
    __syncthreads();

    // Phase B: one global reservation per (block, n); reuse lcnt as local offset
    if (t < N_DIM) {
        int c = lcnt[t];
        gbase[t] = (c > 0) ? atomicAdd(&cnt[b * N_DIM + t], c) : 0;
        lcnt[t] = 0;
    }
    __syncthreads();

    // Phase C: write pairs at reserved positions
    if (inrange && l >= 32) {
        unsigned long long m = m0;
        while (m) {
            int n = __ffsll((long long)m) - 1; m &= m - 1;
            int pos = gbase[n] + atomicAdd(&lcnt[n], 1);
            if (pos < CAP) bucket[(size_t)(b * N_DIM + n) * CAP + pos] = (unsigned short)l;
        }
        m = m1;
        while (m) {
            int n = __ffsll((long long)m) - 1; m &= m - 1;
            int pos = gbase[n + 64] + atomicAdd(&lcnt[n + 64], 1);
            if (pos < CAP) bucket[(size_t)(b * N_DIM + n + 64) * CAP + pos] = (unsigned short)l;
        }
    }
}

// K_top13: one 256-thread block per (gt n, batch b). Score 32 seeds + bucket
// candidates, per-thread 13-deep sorted reg list, per-wave shuffle head-merge,
// one barrier, single-wave final merge of 4x13 heads; atomicOr posbits.
__global__ __launch_bounds__(256) void k_top13(
    const float* __restrict__ psc, const float* __restrict__ pbox,
    const float* __restrict__ pts, const int* __restrict__ glbl,
    const float* __restrict__ gbox, const float* __restrict__ gpad,
    const int* __restrict__ cnt, const unsigned short* __restrict__ bucket,
    unsigned long long* __restrict__ posbits)
{
    const int n = blockIdx.x, b = blockIdx.y, t = threadIdx.x;
    if (gpad[b * N_DIM + n] <= 0.0f) return;   // padded GT: uniform block exit

    const float g0 = gbox[(b * N_DIM + n) * 4 + 0];
    const float g1 = gbox[(b * N_DIM + n) * 4 + 1];
    const float g2 = gbox[(b * N_DIM + n) * 4 + 2];
    const float g3 = gbox[(b * N_DIM + n) * 4 + 3];
    int lbl = glbl[b * N_DIM + n];
    lbl = min(max(lbl, 0), C_DIM - 1);
    const float* psb = psc + (size_t)b * L_DIM * C_DIM;
    const float* pbb = pbox + (size_t)b * L_DIM * 4;
    const int bn = b * N_DIM + n;
    const int nc = min(cnt[bn], CAP);

    // per-thread top-13, sorted desc, registers only (guarded unrolled insert)
    unsigned long long key[K_TOP];
    #pragma unroll
    for (int k = 0; k < K_TOP; ++k) key[k] = 0ull;

    for (int i = t; i < nc + 32; i += 256) {
        const int l = (i < 32) ? i : (int)bucket[(size_t)bn * CAP + (i - 32)];
        const float2 ap = reinterpret_cast<const float2*>(pts)[l];
        unsigned long long ck = (unsigned long long)(0xFFFF - l);  // s == 0
        if (ap.x >= g0 && ap.x <= g2 && ap.y >= g1 && ap.y <= g3) {
            const float4 pbv = reinterpret_cast<const float4*>(pbb)[l];
            float iou = iou_pair(g0, g1, g2, g3, pbv.x, pbv.y, pbv.z, pbv.w);
            if (iou > 0.0f) {
                float cs = psb[(size_t)l * C_DIM + lbl];
                double d = (double)iou, d2 = d * d;
                ck = make_key((double)cs * (d2 * d2 * d2), l);
            }
        }
        if (ck > key[K_TOP - 1]) {
            #pragma unroll
            for (int k = 0; k < K_TOP; ++k) {
                unsigned long long hi = key[k] > ck ? key[k] : ck;
                unsigned long long lo = key[k] > ck ? ck : key[k];
                key[k] = hi; ck = lo;
            }
        }
    }

    // per-wave head-merge (4 waves), no barriers
    const int lane = t & 63, wid = t >> 6;
    __shared__ unsigned long long wl[4 * K_TOP];
    #pragma unroll 1
    for (int r = 0; r < K_TOP; ++r) {
        unsigned long long best = key[0];
        #pragma unroll
        for (int d = 1; d < 64; d <<= 1) {
            unsigned long long o = __shfl_xor(best, d, 64);
            best = o > best ? o : best;
        }
        if (key[0] == best && best != 0ull) {  // unique keys -> one winner
            #pragma unroll
            for (int k = 0; k < K_TOP - 1; ++k) key[k] = key[k + 1];
            key[K_TOP - 1] = 0ull;
        }
        if (lane == 0) wl[wid * K_TOP + r] = best;
    }
    __syncthreads();
    if (wid != 0) return;

    // single-wave final merge of 52 heads (1 per lane)
    unsigned long long v = (lane < 4 * K_TOP) ? wl[lane] : 0ull;
    #pragma unroll 1
    for (int r = 0; r < K_TOP; ++r) {
        unsigned long long best = v;
        #pragma unroll
        for (int d = 1; d < 64; d <<= 1) {
            unsigned long long o = __shfl_xor(best, d, 64);
            best = o > best ? o : best;
        }
        if (v == best) v = 0ull;               // winner removed (keys unique, best>0)
        if (lane == 0) {
            int win = 0xFFFF - (int)(best & 0xFFFFull);
            atomicOr(&posbits[((size_t)b * L_DIM + win) * 2 + (n >> 6)],
                     1ULL << (n & 63));
        }
    }
}

// K_assign: one thread per anchor. p = posbits & stored-spatial.
// pcnt<=1 handled inline (no iou on the pcnt==0 bulk). pcnt>1 anchors go to
// an LDS queue and are resolved WAVE-COOPERATIVELY in pass 2: 64 lanes compute
// 2 ious each + u64 shfl max-reduce (first-max tie: max iou, tie -> lowest n).
// Rationale: 3.7% conflicted anchors means 91% of waves would take the serial
// 128-iou path per-lane; cooperative pass removes that divergence tax.
__global__ __launch_bounds__(256) void k_assign(
    const float* __restrict__ psc, const float* __restrict__ pbox,
    const int* __restrict__ glbl, const float* __restrict__ gbox,
    const unsigned long long* __restrict__ posbits,
    const ulonglong2* __restrict__ spat,
    const int* __restrict__ bgp,
    float* __restrict__ out_lab, float* __restrict__ out_box,
    int* __restrict__ fin_out, float* __restrict__ alat,
    float* __restrict__ maxal, float* __restrict__ maxio)
{
    const int b = blockIdx.y, t = threadIdx.x;
    const int l = blockIdx.x * 256 + t;
    __shared__ float4 gb[N_DIM];
    __shared__ int    gl[N_DIM];
    __shared__ int    qlist[256];
    __shared__ int    qn;
    if (t == 0) qn = 0;
    if (t < N_DIM) {
        gb[t] = reinterpret_cast<const float4*>(gbox)[(size_t)b * N_DIM + t];
        gl[t] = glbl[b * N_DIM + t];
    }
    __syncthreads();

    // ---- pass 1: per-thread; conflicted anchors deferred to LDS queue ----
    if (l < L_DIM) {
        const size_t bl = (size_t)b * L_DIM + l;
        const unsigned long long w0 = posbits[bl * 2 + 0];
        const unsigned long long w1 = posbits[bl * 2 + 1];
        const ulonglong2 sm = spat[bl];
        const unsigned long long p0 = w0 & sm.x, p1 = w1 & sm.y;
        const int pcnt = __popcll(p0) + __popcll(p1);

        if (pcnt <= 1) {
            int fin = (pcnt == 1) ? (p0 ? (__ffsll(p0) - 1) : (64 + __ffsll(p1) - 1)) : -1;
            out_lab[bl] = (fin >= 0) ? (float)gl[fin] : (float)bgp[0];
            int gidx = (fin >= 0) ? fin : 0;      // ref gathers boxes with argmax=0 for bg
            reinterpret_cast<float4*>(out_box)[bl] = gb[gidx];
            fin_out[bl] = fin;
            if (fin >= 0) {
                const float4 pb = reinterpret_cast<const float4*>(pbox)[bl];
                float4 g = gb[fin];
                float iou = iou_pair(g.x, g.y, g.z, g.w, pb.x, pb.y, pb.z, pb.w);
                int lb = min(max(gl[fin], 0), C_DIM - 1);
                float cs = psc[bl * C_DIM + lb];
                float al = cs * powf(iou, 6.0f);
                alat[bl] = al;
                // all values >= 0, init 0 -> int-compare == float-compare
                atomicMax((int*)&maxal[b * N_DIM + fin], __float_as_int(al));
                atomicMax((int*)&maxio[b * N_DIM + fin], __float_as_int(iou));
            }
        } else {
            qlist[atomicAdd(&qn, 1)] = l;
        }
    }
    __syncthreads();

    // ---- pass 2: wave-cooperative conflict resolution ----
    const int lane = t & 63, wid = t >> 6;
    const int nq = qn;
    for (int i = wid; i < nq; i += 4) {
        const int ql = qlist[i];
        const size_t bl = (size_t)b * L_DIM + ql;
        const float4 pb = reinterpret_cast<const float4*>(pbox)[bl];  // same addr, broadcast
        // lanes compute iou for n=lane and n=lane+64; pack (iou_bits, 2^32-1-n)
        float4 gA = gb[lane];
        float4 gB = gb[lane + 64];
        float iouA = iou_pair(gA.x, gA.y, gA.z, gA.w, pb.x, pb.y, pb.z, pb.w);
        float iouB = iou_pair(gB.x, gB.y, gB.z, gB.w, pb.x, pb.y, pb.z, pb.w);
        unsigned long long kA = ((unsigned long long)__float_as_uint(iouA) << 32)
                              | (unsigned long long)(0xFFFFFFFFu - (unsigned)lane);
        unsigned long long kB = ((unsigned long long)__float_as_uint(iouB) << 32)
                              | (unsigned long long)(0xFFFFFFFFu - (unsigned)(lane + 64));
        unsigned long long k = kA > kB ? kA : kB;   // iou in [0,1] -> bits monotone
        #pragma unroll
        for (int d = 1; d < 64; d <<= 1) {
            unsigned long long o = __shfl_xor(k, d, 64);
            k = o > k ? o : k;
        }
        if (lane == 0) {
            int bestn = (int)(0xFFFFFFFFu - (unsigned)(k & 0xFFFFFFFFull));
            float bestiou = __uint_as_float((unsigned)(k >> 32));
            const unsigned long long w0 = posbits[bl * 2 + 0];
            const unsigned long long w1 = posbits[bl * 2 + 1];
            const ulonglong2 sm = spat[bl];
            const unsigned long long p0 = w0 & sm.x, p1 = w1 & sm.y;
            bool posbest = (bestn < 64) ? ((p0 >> bestn) & 1ull) : ((p1 >> (bestn - 64)) & 1ull);
            int fin = posbest ? bestn : -1;
            out_lab[bl] = (fin >= 0) ? (float)gl[fin] : (float)bgp[0];
            int gidx = (fin >= 0) ? fin : 0;
            reinterpret_cast<float4*>(out_box)[bl] = gb[gidx];
            fin_out[bl] = fin;
            if (fin >= 0) {
                int lb = min(max(gl[fin], 0), C_DIM - 1);
                float cs = psc[bl * C_DIM + lb];
                float al = cs * powf(bestiou, 6.0f);
                alat[bl] = al;
                atomicMax((int*)&maxal[b * N_DIM + fin], __float_as_int(al));
                atomicMax((int*)&maxio[b * N_DIM + fin], __float_as_int(bestiou));
            }
        }
    }
}

// K_out: fused norm + one-hot score fill. 16 anchors per block: threads 0..15
// compute nf/cls into LDS, then 320 coalesced float4 stores (C=80 -> 20/anchor).
__global__ __launch_bounds__(256) void k_out(
    const int* __restrict__ fin_out, const float* __restrict__ alat,
    const float* __restrict__ maxal, const float* __restrict__ maxio,
    const int* __restrict__ glbl,
    float* __restrict__ outs)
{
    const int APB = 16;
    const int a0 = blockIdx.x * APB;
    const int t = threadIdx.x;
    __shared__ float snf[APB];
    __shared__ int   scl[APB];
    if (t < APB) {
        int a = a0 + t;
        float v = 0.0f; int c = -1;
        if (a < B_DIM * L_DIM) {
            int b = a / L_DIM;
            int fin = fin_out[a];
            if (fin >= 0) {
                v = alat[a] / (maxal[b * N_DIM + fin] + EPS_F) * maxio[b * N_DIM + fin];
                c = glbl[b * N_DIM + fin];
            }
        }
        snf[t] = v; scl[t] = c;
    }
    __syncthreads();
    float4* out4 = reinterpret_cast<float4*>(outs);
    for (int j = t; j < APB * 20; j += 256) {
        int ai = j / 20;                      // anchor within block
        int a = a0 + ai;
        if (a >= B_DIM * L_DIM) continue;
        int c0 = (j - ai * 20) * 4;
        float v = snf[ai]; int cl = scl[ai];
        float4 o;
        o.x = (c0 + 0 == cl) ? v : 0.0f;
        o.y = (c0 + 1 == cl) ? v : 0.0f;
        o.z = (c0 + 2 == cl) ? v : 0.0f;
        o.w = (c0 + 3 == cl) ? v : 0.0f;
        out4[(size_t)a * 20 + (j - ai * 20)] = o;
    }
}

extern "C" void kernel_launch(void* const* d_in, const int* in_sizes, int n_in,
                              void* d_out, int out_size, void* d_ws, size_t ws_size,
                              hipStream_t stream)
{
    const float* psc  = (const float*)d_in[0];   // [B,L,C]
    const float* pbox = (const float*)d_in[1];   // [B,L,4]
    const float* pts  = (const float*)d_in[2];   // [1,L,2]
    const int*   glbl = (const int*)d_in[3];     // [B,N,1]
    const float* gbox = (const float*)d_in[4];   // [B,N,4]
    const float* gpad = (const float*)d_in[5];   // [B,N,1]
    const int*   bgp  = (const int*)d_in[6];     // scalar (=C)

    // workspace layout (16-byte aligned blocks)
    const size_t P = (size_t)B_DIM * L_DIM * 2 * sizeof(unsigned long long); // 4,300,800
    char* w = (char*)d_ws;
    unsigned long long* posbits = (unsigned long long*)w;                    // P bytes
    float* maxal = (float*)(w + P);                                          // 4096 B
    float* maxio = (float*)(w + P + 4096);                                   // 4096 B
    int*   cnt   = (int*)  (w + P + 8192);                                   // 4096 B
    ulonglong2* spat = (ulonglong2*)(w + P + 12288);                         // P bytes
    int*   fin   = (int*)  (w + 2 * P + 12288);                              // 1,075,200 B
    float* alat  = (float*)(w + 2 * P + 12288 + 1075200);                    // 1,075,200 B
    unsigned short* bucket = (unsigned short*)(w + 2 * P + 12288 + 2 * 1075200); // 8 MB

    float* out_lab = (float*)d_out;                              // [B,L]
    float* out_box = out_lab + (size_t)B_DIM * L_DIM;            // [B,L,4]
    float* out_sc  = out_box + (size_t)B_DIM * L_DIM * 4;        // [B,L,C]

    // all accumulated regions zeroed on-device every call:
    //   cnt/maxal/maxio by k_zero; posbits inline in k_push (pre-k_top13).
    k_zero<<<dim3(1), dim3(1024), 0, stream>>>(cnt, maxal, maxio);
    k_push<<<dim3((L_DIM + 255) / 256, B_DIM), dim3(256), 0, stream>>>(
        pts, gbox, gpad, cnt, bucket, spat, (ulonglong2*)posbits);
    k_top13<<<dim3(N_DIM, B_DIM), dim3(256), 0, stream>>>(
        psc, pbox, pts, glbl, gbox, gpad, cnt, bucket, posbits);
    k_assign<<<dim3((L_DIM + 255) / 256, B_DIM), dim3(256), 0, stream>>>(
        psc, pbox, glbl, gbox, posbits, spat, bgp,
        out_lab, out_box, fin, alat, maxal, maxio);
    k_out<<<dim3((B_DIM * L_DIM + 15) / 16), dim3(256), 0, stream>>>(
        fin, alat, maxal, maxio, glbl, out_sc);
}